// Round 1
// baseline (200.935 us; speedup 1.0000x reference)
//
#include <hip/hip_runtime.h>
#include <hip/hip_bf16.h>

// Problem constants (hardcoded from setup_inputs; n_shifts == T == 64)
#define NB   4096
#define NT   64
#define NDIM 16
#define NH1  256
#define NH2  256
#define NLAT 64
#define NKD  80
#define YROW (NT * NKD)   // 5120 floats per batch row of y / y_pred

typedef __attribute__((ext_vector_type(8))) short bf16x8;
typedef __attribute__((ext_vector_type(4))) float f32x4;

static __device__ __forceinline__ short f2bf(float f) {
  union { float f; unsigned u; } v; v.f = f;
  unsigned r = v.u + 0x7fffu + ((v.u >> 16) & 1u);   // RNE
  return (short)(r >> 16);
}

static __device__ __forceinline__ void async_copy16(void* lds_dst, const void* g_src) {
  __builtin_amdgcn_global_load_lds(
      (const __attribute__((address_space(1))) unsigned int*)g_src,
      (__attribute__((address_space(3))) unsigned int*)lds_dst, 16, 0, 0);
}

// ---------------------------------------------------------------------------
// Prep: rearrange weights into MFMA B-fragment order (bf16) in workspace.
// B-frag for mfma_f32_16x16x32_bf16: lane l holds B[k][n] with n = l&15,
// k = 8*(l>>4)+e (e=0..7). B = W^T, so element = W[ntile*16 + (l&15)][k].
// ws layout (shorts): [0)      W2frag  [kk8][nt16][lane64][e8] = 65536
//                     [65536)  W3frag  [kk8][nt4 ][lane64][e8] = 16384
//                     [81920)  W1frag  [nt16][lane64][e8] (k>=16 -> 0) = 8192
// ---------------------------------------------------------------------------
__global__ __launch_bounds__(256) void prep_kernel(const float* __restrict__ W1,
                                                   const float* __restrict__ W2,
                                                   const float* __restrict__ W3,
                                                   short* __restrict__ ws) {
  int i = blockIdx.x * 256 + threadIdx.x;   // 0..65535
  {
    int e = i & 7, l = (i >> 3) & 63, nt = (i >> 9) & 15, kk = i >> 13;
    int g = nt * 16 + (l & 15);
    int h = kk * 32 + (l >> 4) * 8 + e;
    ws[i] = f2bf(W2[g * NH1 + h]);
  }
  if (i < 16384) {
    int e = i & 7, l = (i >> 3) & 63, nt = (i >> 9) & 3, kk = i >> 11;
    int g = nt * 16 + (l & 15);
    int h = kk * 32 + (l >> 4) * 8 + e;
    ws[65536 + i] = f2bf(W3[g * NH2 + h]);
  }
  if (i < 8192) {
    int e = i & 7, l = (i >> 3) & 63, nt = i >> 9;
    int g = nt * 16 + (l & 15);
    int k = (l >> 4) * 8 + e;
    ws[81920 + i] = (k < NDIM) ? f2bf(W1[g * NDIM + k]) : (short)0;
  }
}

// ---------------------------------------------------------------------------
// MLP: one block = one batch row (64 tokens), 256 threads = 4 waves.
// Wave w owns token M-tile w (tokens 16w..16w+15).
// LDS carve (bytes):
//   xf   [64][16] f32          @ 0      (4096)
//   xb   [64][40] bf16         @ 4096   (5120)   k padded to 32, stride 40
//   h1s  [64][264] bf16        @ 9216   (33792)  row stride 528B
//   h2s  [64][264] bf16        @ 43008  (33792)
//   chk  2 x 16KB bf16         @ 76800  (32768)  W2 chunk double buffer
//   ys   [64][80] f32          @ 9216   overlays dead h1s
// total 109568 B -> 1 block/CU
// ---------------------------------------------------------------------------
__global__ __launch_bounds__(256) void mlp_kernel(const float* __restrict__ x,
                                                  const float* __restrict__ b1g,
                                                  const float* __restrict__ b2g,
                                                  const short* __restrict__ ws,
                                                  float* __restrict__ y) {
  extern __shared__ char smem[];
  float* xf  = (float*)smem;
  short* xb  = (short*)(smem + 4096);
  short* h1s = (short*)(smem + 9216);
  short* h2s = (short*)(smem + 43008);
  short* chk = (short*)(smem + 76800);
  float* ys  = (float*)(smem + 9216);

  const int tid  = threadIdx.x;
  const int lane = tid & 63;
  const int w    = tid >> 6;
  const int b    = blockIdx.x;
  const int m16  = lane & 15;
  const int kg   = lane >> 4;

  const short* W2f = ws;
  const short* W3f = ws + 65536;
  const short* W1f = ws + 81920;

  // ---- load x tile: 1024 floats, one float4 per thread ----
  {
    const float4 v = ((const float4*)(x + (long)b * (NT * NDIM)))[tid];
    int t0 = tid >> 2, d0 = (tid & 3) * 4;
    *(float4*)(xf + t0 * 16 + d0) = v;
    short* p = xb + t0 * 40 + d0;
    p[0] = f2bf(v.x); p[1] = f2bf(v.y); p[2] = f2bf(v.z); p[3] = f2bf(v.w);
    short* q = xb + t0 * 40 + 16 + d0;     // zero pad k=16..31
    q[0] = 0; q[1] = 0; q[2] = 0; q[3] = 0;
  }
  __syncthreads();

  // ---- fire staging of W2 chunk 0 into half 0 (hides under GEMM1) ----
  {
    const char* src = (const char*)W2f;
#pragma unroll
    for (int c = 0; c < 4; ++c) {
      int off = (w * 4 + c) * 1024;
      async_copy16((char*)chk + off, src + off + lane * 16);
    }
  }

  // ---- GEMM1: h1 = relu(x @ W1^T + b1), K=32 (padded), 16 N-tiles ----
  {
    const bf16x8 a = *(const bf16x8*)(xb + (w * 16 + m16) * 40 + kg * 8);
#pragma unroll
    for (int nt = 0; nt < 16; ++nt) {
      const bf16x8 bb = *(const bf16x8*)(W1f + (nt * 64 + lane) * 8);
      f32x4 acc = {0.f, 0.f, 0.f, 0.f};
      acc = __builtin_amdgcn_mfma_f32_16x16x32_bf16(a, bb, acc, 0, 0, 0);
      const float bias = b1g[nt * 16 + m16];
#pragma unroll
      for (int r = 0; r < 4; ++r) {
        float v = acc[r] + bias;
        v = v > 0.f ? v : 0.f;
        h1s[(w * 16 + kg * 4 + r) * 264 + nt * 16 + m16] = f2bf(v);
      }
    }
  }

  // ---- GEMM2: h2 = relu(h1 @ W2^T + b2), K=256 in 8 chunks, double-buffered
  f32x4 acc2[16];
#pragma unroll
  for (int nt = 0; nt < 16; ++nt) acc2[nt] = (f32x4){0.f, 0.f, 0.f, 0.f};

  for (int kk = 0; kk < 8; ++kk) {
    __syncthreads();   // chunk kk staged (vmcnt drain) + prev buffer consumed
    if (kk < 7) {
      const char* src = (const char*)(W2f + (kk + 1) * 8192);
      char* dst = (char*)chk + ((kk + 1) & 1) * 16384;
#pragma unroll
      for (int c = 0; c < 4; ++c) {
        int off = (w * 4 + c) * 1024;
        async_copy16(dst + off, src + off + lane * 16);
      }
    }
    const short* cb = chk + (kk & 1) * 8192;
    const bf16x8 a = *(const bf16x8*)(h1s + (w * 16 + m16) * 264 + kk * 32 + kg * 8);
#pragma unroll
    for (int nt = 0; nt < 16; ++nt) {
      const bf16x8 bb = *(const bf16x8*)(cb + (nt * 64 + lane) * 8);
      acc2[nt] = __builtin_amdgcn_mfma_f32_16x16x32_bf16(a, bb, acc2[nt], 0, 0, 0);
    }
  }
  // epilogue -> h2s (bf16)
#pragma unroll
  for (int nt = 0; nt < 16; ++nt) {
    const float bias = b2g[nt * 16 + m16];
#pragma unroll
    for (int r = 0; r < 4; ++r) {
      float v = acc2[nt][r] + bias;
      v = v > 0.f ? v : 0.f;
      h2s[(w * 16 + kg * 4 + r) * 264 + nt * 16 + m16] = f2bf(v);
    }
  }

  __syncthreads();   // all h1s reads done -> safe to overlay ys; h2s visible

  // ---- x (f32, exact) -> ys cols 0..15 ----
  {
    int t0 = tid >> 2, d0 = (tid & 3) * 4;
    *(float4*)(ys + t0 * 80 + d0) = *(const float4*)(xf + t0 * 16 + d0);
  }

  // ---- GEMM3: g = h2 @ W3^T, B-frags direct from global (32KB, L2-hot) ----
  f32x4 acc3[4];
#pragma unroll
  for (int nt = 0; nt < 4; ++nt) acc3[nt] = (f32x4){0.f, 0.f, 0.f, 0.f};
#pragma unroll
  for (int kk = 0; kk < 8; ++kk) {
    const bf16x8 a = *(const bf16x8*)(h2s + (w * 16 + m16) * 264 + kk * 32 + kg * 8);
#pragma unroll
    for (int nt = 0; nt < 4; ++nt) {
      const bf16x8 bb = *(const bf16x8*)(W3f + ((kk * 4 + nt) * 64 + lane) * 8);
      acc3[nt] = __builtin_amdgcn_mfma_f32_16x16x32_bf16(a, bb, acc3[nt], 0, 0, 0);
    }
  }
  // epilogue: g -> ys cols 16..79 (f32)
#pragma unroll
  for (int nt = 0; nt < 4; ++nt)
#pragma unroll
    for (int r = 0; r < 4; ++r)
      ys[(w * 16 + kg * 4 + r) * 80 + 16 + nt * 16 + m16] = acc3[nt][r];

  __syncthreads();

  // ---- coalesced store of y tile: 1280 float4 ----
  float4* yg = (float4*)(y + (long)b * YROW);
  const float4* ysv = (const float4*)ys;
#pragma unroll
  for (int i = 0; i < 5; ++i)
    yg[i * 256 + tid] = ysv[i * 256 + tid];
}

// ---------------------------------------------------------------------------
// Scan: y_pred[b, t] = y_pred[b, t-1] @ K^T, 63 serial steps.
// Block = 8 batch rows, 320 threads: thread owns output column c = tid%80
// (K row K[c][:] held in 80 VGPRs) for rows rg and rg+4 (rg = tid/80).
// ---------------------------------------------------------------------------
__global__ __launch_bounds__(320) void scan_kernel(const float* __restrict__ Kg,
                                                   const float* __restrict__ y,
                                                   float* __restrict__ yp) {
  __shared__ float buf[2][8][80];
  const int tid = threadIdx.x;
  const int c   = tid % 80;
  const int rg  = tid / 80;          // 0..3
  const int b0  = blockIdx.x * 8;

  float4 Kv[20];
  const float4* kp = (const float4*)(Kg + c * 80);
#pragma unroll
  for (int j = 0; j < 20; ++j) Kv[j] = kp[j];

  // load y0 rows (t=0 of y), write y_pred[:,0,:], fill buf[0]
#pragma unroll
  for (int i = 0; i < 2; ++i) {
    int o = i * 320 + tid;           // 0..639
    int r = o / 80, cc = o - r * 80;
    float v = y[(b0 + r) * YROW + cc];
    buf[0][r][cc] = v;
    yp[(b0 + r) * YROW + cc] = v;
  }
  __syncthreads();

  int cur = 0;
  for (int t = 1; t < 64; ++t) {
    const float* r0 = buf[cur][rg];
    const float* r1 = buf[cur][rg + 4];
    float a0 = 0.f, a1 = 0.f;
#pragma unroll
    for (int j = 0; j < 20; ++j) {
      float4 kv = Kv[j];
      float4 v0 = *(const float4*)(r0 + j * 4);
      float4 v1 = *(const float4*)(r1 + j * 4);
      a0 += v0.x * kv.x; a1 += v1.x * kv.x;
      a0 += v0.y * kv.y; a1 += v1.y * kv.y;
      a0 += v0.z * kv.z; a1 += v1.z * kv.z;
      a0 += v0.w * kv.w; a1 += v1.w * kv.w;
    }
    buf[cur ^ 1][rg][c] = a0;
    buf[cur ^ 1][rg + 4][c] = a1;
    yp[(b0 + rg) * YROW + t * 80 + c] = a0;
    yp[(b0 + rg + 4) * YROW + t * 80 + c] = a1;
    __syncthreads();
    cur ^= 1;
  }
}

extern "C" void kernel_launch(void* const* d_in, const int* in_sizes, int n_in,
                              void* d_out, int out_size, void* d_ws, size_t ws_size,
                              hipStream_t stream) {
  const float* x  = (const float*)d_in[0];
  const float* W1 = (const float*)d_in[1];
  const float* b1 = (const float*)d_in[2];
  const float* W2 = (const float*)d_in[3];
  const float* b2 = (const float*)d_in[4];
  const float* W3 = (const float*)d_in[5];
  const float* Kg = (const float*)d_in[6];
  float* y  = (float*)d_out;
  float* yp = y + (long)NB * YROW;
  short* ws = (short*)d_ws;

  prep_kernel<<<256, 256, 0, stream>>>(W1, W2, W3, ws);
  mlp_kernel<<<NB, 256, 109568, stream>>>(x, b1, b2, ws, y);
  scan_kernel<<<NB / 8, 320, 0, stream>>>(Kg, y, yp);
}

// Round 2
// 136.372 us; speedup vs baseline: 1.4734x; 1.4734x over previous
//
#include <hip/hip_runtime.h>
#include <hip/hip_bf16.h>

// Problem constants (hardcoded from setup_inputs; n_shifts == T == 64)
#define NB   4096
#define NT   64
#define NDIM 16
#define NH1  256
#define NH2  256
#define NLAT 64
#define NKD  80
#define YROW (NT * NKD)   // 5120 floats per batch row of y / y_pred

typedef __attribute__((ext_vector_type(8))) short bf16x8;
typedef __attribute__((ext_vector_type(4))) float f32x4;

static __device__ __forceinline__ short f2bf(float f) {
  union { float f; unsigned u; } v; v.f = f;
  unsigned r = v.u + 0x7fffu + ((v.u >> 16) & 1u);   // RNE
  return (short)(r >> 16);
}

// ---------------------------------------------------------------------------
// Prep: rearrange weights into MFMA B-fragment order (bf16) in workspace.
// B-frag for mfma_f32_16x16x32_bf16: lane l holds B[k][n] with n = l&15,
// k = 8*(l>>4)+e (e=0..7). B = W^T, so element = W[ntile*16 + (l&15)][k].
// ws layout (shorts): [0)      W2frag  [kk8][nt16][lane64][e8] = 65536
//                     [65536)  W3frag  [kk8][nt4 ][lane64][e8] = 16384
//                     [81920)  W1frag  [nt16][lane64][e8] (k>=16 -> 0) = 8192
// ---------------------------------------------------------------------------
__global__ __launch_bounds__(256) void prep_kernel(const float* __restrict__ W1,
                                                   const float* __restrict__ W2,
                                                   const float* __restrict__ W3,
                                                   short* __restrict__ ws) {
  int i = blockIdx.x * 256 + threadIdx.x;   // 0..65535
  {
    int e = i & 7, l = (i >> 3) & 63, nt = (i >> 9) & 15, kk = i >> 13;
    int g = nt * 16 + (l & 15);
    int h = kk * 32 + (l >> 4) * 8 + e;
    ws[i] = f2bf(W2[g * NH1 + h]);
  }
  if (i < 16384) {
    int e = i & 7, l = (i >> 3) & 63, nt = (i >> 9) & 3, kk = i >> 11;
    int g = nt * 16 + (l & 15);
    int h = kk * 32 + (l >> 4) * 8 + e;
    ws[65536 + i] = f2bf(W3[g * NH2 + h]);
  }
  if (i < 8192) {
    int e = i & 7, l = (i >> 3) & 63, nt = i >> 9;
    int g = nt * 16 + (l & 15);
    int k = (l >> 4) * 8 + e;
    ws[81920 + i] = (k < NDIM) ? f2bf(W1[g * NDIM + k]) : (short)0;
  }
}

// ---------------------------------------------------------------------------
// MLP: one block = TWO batch rows (128 tokens), 512 threads = 8 waves.
// N-split: GEMM1/2: wave w owns ntiles {2w, 2w+1} for all 8 M-tiles.
//          GEMM3:   wave w owns ntile w&3, M-tiles (w>>2)*4 .. +3.
// B-fragments load DIRECTLY from global (L2-resident, each frag read once
// per block) -> no LDS weight staging, no double-buffer barriers.
// LDS carve (bytes):
//   xb   [128][40] bf16   @ 0      (10240)  k padded to 32
//   h1s  [128][264] bf16  @ 10240  (67584)  row stride 528B (2-way conflicts)
//   h2s  overlays h1s (acc2 in regs across the barrier)
//   ys   [128][80] f32 overlays h2s (acc3 in regs across the barrier)
// total 77824 B -> 2 blocks/CU -> 16 waves/CU (4/SIMD)
// ---------------------------------------------------------------------------
__global__ __launch_bounds__(512, 4) void mlp_kernel(const float* __restrict__ x,
                                                     const float* __restrict__ b1g,
                                                     const float* __restrict__ b2g,
                                                     const short* __restrict__ ws,
                                                     float* __restrict__ y) {
  extern __shared__ char smem[];
  short* xb  = (short*)smem;
  short* h1s = (short*)(smem + 10240);
  short* h2s = h1s;                     // overlay (guarded by barriers)
  float* ys  = (float*)(smem + 10240);  // overlay (guarded by barriers)

  const int tid  = threadIdx.x;
  const int lane = tid & 63;
  const int w    = tid >> 6;            // 0..7
  const int m16  = lane & 15;
  const int kg   = lane >> 4;
  const long b   = blockIdx.x;          // 0..2047 (2 batch rows each)

  const short* W2f = ws;
  const short* W3f = ws + 65536;
  const short* W1f = ws + 81920;

  // ---- load x tile (2048 floats), keep xv in regs for the y epilogue ----
  const float4 xv = ((const float4*)(x + b * 2048))[tid];
  {
    int t0 = tid >> 2, d0 = (tid & 3) * 4;
    short* p = xb + t0 * 40 + d0;
    p[0] = f2bf(xv.x); p[1] = f2bf(xv.y); p[2] = f2bf(xv.z); p[3] = f2bf(xv.w);
    short* q = xb + t0 * 40 + 16 + d0;     // zero pad k=16..31
    q[0] = 0; q[1] = 0; q[2] = 0; q[3] = 0;
  }
  __syncthreads();

  // ---- GEMM1: h1 = relu(x @ W1^T + b1); wave w -> ntiles 2w, 2w+1 ----
  {
    const bf16x8 bb0 = *(const bf16x8*)(W1f + ((2 * w) * 64 + lane) * 8);
    const bf16x8 bb1 = *(const bf16x8*)(W1f + ((2 * w + 1) * 64 + lane) * 8);
    const float bias0 = b1g[(2 * w) * 16 + m16];
    const float bias1 = b1g[(2 * w + 1) * 16 + m16];
#pragma unroll
    for (int mt = 0; mt < 8; ++mt) {
      const bf16x8 a = *(const bf16x8*)(xb + (mt * 16 + m16) * 40 + kg * 8);
      f32x4 c0 = {0.f, 0.f, 0.f, 0.f}, c1 = {0.f, 0.f, 0.f, 0.f};
      c0 = __builtin_amdgcn_mfma_f32_16x16x32_bf16(a, bb0, c0, 0, 0, 0);
      c1 = __builtin_amdgcn_mfma_f32_16x16x32_bf16(a, bb1, c1, 0, 0, 0);
      short* row = h1s + (mt * 16 + kg * 4) * 264;
#pragma unroll
      for (int r = 0; r < 4; ++r) {
        float v0 = c0[r] + bias0; v0 = v0 > 0.f ? v0 : 0.f;
        float v1 = c1[r] + bias1; v1 = v1 > 0.f ? v1 : 0.f;
        row[r * 264 + (2 * w) * 16 + m16]     = f2bf(v0);
        row[r * 264 + (2 * w + 1) * 16 + m16] = f2bf(v1);
      }
    }
  }
  __syncthreads();

  // ---- GEMM2: h2 = relu(h1 @ W2^T + b2); K=256, B-frags direct from L2 ----
  f32x4 acc2[8][2];
#pragma unroll
  for (int mt = 0; mt < 8; ++mt) {
    acc2[mt][0] = (f32x4){0.f, 0.f, 0.f, 0.f};
    acc2[mt][1] = (f32x4){0.f, 0.f, 0.f, 0.f};
  }
  for (int kk = 0; kk < 8; ++kk) {
    const bf16x8 bb0 = *(const bf16x8*)(W2f + ((kk * 16 + 2 * w) * 64 + lane) * 8);
    const bf16x8 bb1 = *(const bf16x8*)(W2f + ((kk * 16 + 2 * w + 1) * 64 + lane) * 8);
#pragma unroll
    for (int mt = 0; mt < 8; ++mt) {
      const bf16x8 a = *(const bf16x8*)(h1s + (mt * 16 + m16) * 264 + kk * 32 + kg * 8);
      acc2[mt][0] = __builtin_amdgcn_mfma_f32_16x16x32_bf16(a, bb0, acc2[mt][0], 0, 0, 0);
      acc2[mt][1] = __builtin_amdgcn_mfma_f32_16x16x32_bf16(a, bb1, acc2[mt][1], 0, 0, 0);
    }
  }
  __syncthreads();   // all h1s reads complete -> safe to overlay h2s
  {
    const float bias0 = b2g[(2 * w) * 16 + m16];
    const float bias1 = b2g[(2 * w + 1) * 16 + m16];
#pragma unroll
    for (int mt = 0; mt < 8; ++mt) {
      short* row = h2s + (mt * 16 + kg * 4) * 264;
#pragma unroll
      for (int r = 0; r < 4; ++r) {
        float v0 = acc2[mt][0][r] + bias0; v0 = v0 > 0.f ? v0 : 0.f;
        float v1 = acc2[mt][1][r] + bias1; v1 = v1 > 0.f ? v1 : 0.f;
        row[r * 264 + (2 * w) * 16 + m16]     = f2bf(v0);
        row[r * 264 + (2 * w + 1) * 16 + m16] = f2bf(v1);
      }
    }
  }
  __syncthreads();

  // ---- GEMM3: g = h2 @ W3^T; wave w -> ntile w&3, mtiles (w>>2)*4.. ----
  const int nt3 = w & 3;
  const int mb  = (w >> 2) * 4;
  f32x4 acc3[4];
#pragma unroll
  for (int m = 0; m < 4; ++m) acc3[m] = (f32x4){0.f, 0.f, 0.f, 0.f};
  for (int kk = 0; kk < 8; ++kk) {
    const bf16x8 bb = *(const bf16x8*)(W3f + ((kk * 4 + nt3) * 64 + lane) * 8);
#pragma unroll
    for (int m = 0; m < 4; ++m) {
      const bf16x8 a = *(const bf16x8*)(h2s + ((mb + m) * 16 + m16) * 264 + kk * 32 + kg * 8);
      acc3[m] = __builtin_amdgcn_mfma_f32_16x16x32_bf16(a, bb, acc3[m], 0, 0, 0);
    }
  }
  __syncthreads();   // all h2s reads complete -> safe to overlay ys

  // ---- assemble y tile in LDS: x part (exact f32 from regs) + g part ----
  {
    int t0 = tid >> 2, d0 = (tid & 3) * 4;
    *(float4*)(ys + t0 * 80 + d0) = xv;
  }
#pragma unroll
  for (int m = 0; m < 4; ++m)
#pragma unroll
    for (int r = 0; r < 4; ++r)
      ys[((mb + m) * 16 + kg * 4 + r) * 80 + 16 + nt3 * 16 + m16] = acc3[m][r];
  __syncthreads();

  // ---- coalesced store of y tile: 2560 float4 over 512 threads ----
  float4* yg = (float4*)(y + b * (2 * YROW));
  const float4* ysv = (const float4*)ys;
#pragma unroll
  for (int i = 0; i < 5; ++i)
    yg[i * 512 + tid] = ysv[i * 512 + tid];
}

// ---------------------------------------------------------------------------
// Scan: y_pred[b, t] = y_pred[b, t-1] @ K^T, 63 serial steps.
// Block = 8 batch rows, 320 threads: thread owns output column c = tid%80
// (K row K[c][:] held in 80 VGPRs) for rows rg and rg+4 (rg = tid/80).
// 4 independent accumulator chains per row (component-wise) to cut the
// serial FMA dependency from 80 deep to 20.
// ---------------------------------------------------------------------------
__global__ __launch_bounds__(320) void scan_kernel(const float* __restrict__ Kg,
                                                   const float* __restrict__ y,
                                                   float* __restrict__ yp) {
  __shared__ float buf[2][8][80];
  const int tid = threadIdx.x;
  const int c   = tid % 80;
  const int rg  = tid / 80;          // 0..3
  const int b0  = blockIdx.x * 8;

  float4 Kv[20];
  const float4* kp = (const float4*)(Kg + c * 80);
#pragma unroll
  for (int j = 0; j < 20; ++j) Kv[j] = kp[j];

  // load y0 rows (t=0 of y), write y_pred[:,0,:], fill buf[0]
#pragma unroll
  for (int i = 0; i < 2; ++i) {
    int o = i * 320 + tid;           // 0..639
    int r = o / 80, cc = o - r * 80;
    float v = y[(b0 + r) * YROW + cc];
    buf[0][r][cc] = v;
    yp[(b0 + r) * YROW + cc] = v;
  }
  __syncthreads();

  float* yp0 = yp + (long)(b0 + rg) * YROW + c;
  float* yp1 = yp + (long)(b0 + rg + 4) * YROW + c;

  int cur = 0;
  for (int t = 1; t < 64; ++t) {
    const float* r0 = buf[cur][rg];
    const float* r1 = buf[cur][rg + 4];
    float a00 = 0.f, a01 = 0.f, a02 = 0.f, a03 = 0.f;
    float a10 = 0.f, a11 = 0.f, a12 = 0.f, a13 = 0.f;
#pragma unroll
    for (int j = 0; j < 20; ++j) {
      float4 kv = Kv[j];
      float4 v0 = *(const float4*)(r0 + j * 4);
      float4 v1 = *(const float4*)(r1 + j * 4);
      a00 += v0.x * kv.x; a10 += v1.x * kv.x;
      a01 += v0.y * kv.y; a11 += v1.y * kv.y;
      a02 += v0.z * kv.z; a12 += v1.z * kv.z;
      a03 += v0.w * kv.w; a13 += v1.w * kv.w;
    }
    float a0 = (a00 + a01) + (a02 + a03);
    float a1 = (a10 + a11) + (a12 + a13);
    buf[cur ^ 1][rg][c] = a0;
    buf[cur ^ 1][rg + 4][c] = a1;
    yp0[t * 80] = a0;
    yp1[t * 80] = a1;
    __syncthreads();
    cur ^= 1;
  }
}

extern "C" void kernel_launch(void* const* d_in, const int* in_sizes, int n_in,
                              void* d_out, int out_size, void* d_ws, size_t ws_size,
                              hipStream_t stream) {
  const float* x  = (const float*)d_in[0];
  const float* W1 = (const float*)d_in[1];
  const float* b1 = (const float*)d_in[2];
  const float* W2 = (const float*)d_in[3];
  const float* b2 = (const float*)d_in[4];
  const float* W3 = (const float*)d_in[5];
  const float* Kg = (const float*)d_in[6];
  float* y  = (float*)d_out;
  float* yp = y + (long)NB * YROW;
  short* ws = (short*)d_ws;

  prep_kernel<<<256, 256, 0, stream>>>(W1, W2, W3, ws);
  mlp_kernel<<<NB / 2, 512, 77824, stream>>>(x, b1, b2, ws, y);
  scan_kernel<<<NB / 8, 320, 0, stream>>>(Kg, y, yp);
}